// Round 15
// baseline (158.927 us; speedup 1.0000x reference)
//
#include <hip/hip_runtime.h>
#include <cstdint>

#define A_DIM 1024
#define B_DIM 64
#define H_DIM 512

typedef float f32x4 __attribute__((ext_vector_type(4)));

// ---------------- ws layout (float offsets) ----------------
// P1  : 16 slabs * 64 * 1024 = 1,048,576  [0]
//       slabs 0..3: df kq-partials (summed inline in k24)
//       slabs 4..7: dfi kq-partials (summed inline in k24)
//       slabs 8..15: g3/g4 partials (summed inline in k5b)
// P4  : 2560 * 1024 = 2,621,440  [1,048,576]   (ctx partials; dead after k34)
// P5  : 8 * 65536   =   524,288  [1,048,576]   (reuses P4 region)
// p_all: 65,536 + 16,384 = 81,920  [3,670,016]
// ctx : 2 * 65,536 = 131,072      [3,751,936]
// total ≈ 15.5 MB (ws is ~1 GB per harness poison fills)
#define WS_P1_OFF   0u
#define WS_P4_OFF   1048576u
#define WS_P5_OFF   1048576u
#define WS_PALL_OFF 3670016u
#define WS_CTX_OFF  3751936u

// d_out layout (floats): ctx_mm[0..65535], attn[65536..131071],
// attn_img[131072..147455], coverage[147456..212991], coverage_img[212992..229375]

__device__ __forceinline__ float ftanh(float x) {
  float xc = fminf(fmaxf(x, -10.f), 10.f);
  float t  = __expf(2.f * xc);
  return (t - 1.f) * __builtin_amdgcn_rcpf(t + 1.f);
}

// Execution-only barrier: lgkmcnt(0) orders LDS writes; vmcnt NOT drained, so
// register prefetches survive the rendezvous. sched_barrier stops hoisting.
__device__ __forceinline__ void barrier_keep_loads() {
  asm volatile("s_waitcnt lgkmcnt(0)" ::: "memory");
  __builtin_amdgcn_s_barrier();
  __builtin_amdgcn_sched_barrier(0);
}

template <bool NTLOAD>
__device__ __forceinline__ f32x4 stream_ld(const f32x4* p) {
  if constexpr (NTLOAD) return __builtin_nontemporal_load(p);
  else return *p;
}

// K1: partials of dec @ {W1..W4}. W rows VECTOR-coalesced, dec uniform
// s_loads. grid = 512 blocks (m x 16 bg x 4 kq x 2 a-half), 128 thr.
__global__ __launch_bounds__(128) void k1_gemm(
    const float* __restrict__ h0, const float* __restrict__ h1,
    const float* __restrict__ W1, const float* __restrict__ W2,
    const float* __restrict__ W3, const float* __restrict__ W4,
    float* __restrict__ P1) {
  int bid = blockIdx.x;            // 0..511
  int m   = bid >> 7;              // 0..3
  int bg  = (bid >> 3) & 15;       // 0..15 (4 batch rows each)
  int kq  = (bid >> 1) & 3;        // 0..3 (k-quarter of 256)
  int ah  = bid & 1;               // 0..1 (a-half of 512)
  const float* W = (m == 0) ? W1 : (m == 1) ? W2 : (m == 2) ? W3 : W4;
  const float* dbase = ((kq < 2) ? h0 : h1) + (kq & 1) * 256;
  const float* Wrow  = W + (size_t)(kq * 256) * A_DIM + ah * 512 + threadIdx.x * 4;

  f32x4 acc[4];
#pragma unroll
  for (int i = 0; i < 4; ++i) acc[i] = (f32x4){0.f, 0.f, 0.f, 0.f};

#pragma unroll 2
  for (int k4 = 0; k4 < 256; k4 += 4) {
    f32x4 w0 = *reinterpret_cast<const f32x4*>(Wrow + (size_t)(k4 + 0) * A_DIM);
    f32x4 w1 = *reinterpret_cast<const f32x4*>(Wrow + (size_t)(k4 + 1) * A_DIM);
    f32x4 w2 = *reinterpret_cast<const f32x4*>(Wrow + (size_t)(k4 + 2) * A_DIM);
    f32x4 w3 = *reinterpret_cast<const f32x4*>(Wrow + (size_t)(k4 + 3) * A_DIM);
#pragma unroll
    for (int i = 0; i < 4; ++i) {
      int b = bg * 4 + i;
      f32x4 d = *reinterpret_cast<const f32x4*>(dbase + (size_t)b * H_DIM + k4);
      acc[i] += d.x * w0;
      acc[i] += d.y * w1;
      acc[i] += d.z * w2;
      acc[i] += d.w * w3;
    }
  }
#pragma unroll
  for (int i = 0; i < 4; ++i) {
    int b = bg * 4 + i;
    *reinterpret_cast<f32x4*>(
        P1 + ((size_t)(m * 4 + kq) * 64 + b) * A_DIM + ah * 512 + threadIdx.x * 4) = acc[i];
  }
}

// K24 pipeline body, 256-THREAD VARIANT: 32-row chunk = 8 subtiles of 4 rows.
// 4-wave barrier convoys (half of r14's 8) and 4 independent blocks/CU.
// Per subtile t: issue feat(t+1)+O(t+1) prefetches; A(t): 1 row/wave tanh ->
// pl[4t+w]; barrier_keep_loads(); B(t): every thread (owns a-quad tid)
// accumulates the 4 rows.
template <bool NTLOAD>
__device__ __forceinline__ void k24_body(
    const float* feat, const float* osrc, const float* covsrc, const float* msk,
    float* pout, float* P4out, float covscale,
    f32x4* sdf, f32x4* sv, f32x4* swc, float* pl, int tid) {
  int w = tid >> 6, lane = tid & 63;

  // cov/mask: lane t<8 holds row 4t+w (this wave's subtile-t row).
  float covv = 0.f, mskv = 1.f;
  if (lane < 8) {
    int rr = 4 * lane + w;
    covv = covsrc[rr];
    mskv = msk ? msk[rr] : 1.f;
  }

  // V = sum_a |v_a| (deterministic, identical in every wave)
  float Vp = 0.f;
#pragma unroll
  for (int p = 0; p < 4; ++p) {
    f32x4 t = sv[p * 64 + lane];
    Vp += fabsf(t.x) + fabsf(t.y) + fabsf(t.z) + fabsf(t.w);
  }
#pragma unroll
  for (int o = 32; o > 0; o >>= 1) Vp += __shfl_xor(Vp, o);
  float V = Vp;

  const f32x4* F = reinterpret_cast<const f32x4*>(feat);
  const f32x4* O = reinterpret_cast<const f32x4*>(osrc) + tid;  // a-quad = tid
  f32x4 acc4 = {0.f, 0.f, 0.f, 0.f};

  f32x4 cur[4], nxt[4], ob[4], obn[4];
  // prologue: subtile 0
#pragma unroll
  for (int p = 0; p < 4; ++p)
    cur[p] = stream_ld<NTLOAD>(&F[(size_t)w * 256 + p * 64 + lane]);
#pragma unroll
  for (int j = 0; j < 4; ++j)
    ob[j] = stream_ld<NTLOAD>(&O[(size_t)j * 256]);

#pragma unroll
  for (int t = 0; t < 8; ++t) {
    int row = 4 * t + w;
    // prefetch subtile t+1 (both streams) — stays in flight across barrier
    if (t < 7) {
#pragma unroll
      for (int p = 0; p < 4; ++p)
        nxt[p] = stream_ld<NTLOAD>(&F[(size_t)(row + 4) * 256 + p * 64 + lane]);
#pragma unroll
      for (int j = 0; j < 4; ++j)
        obn[j] = stream_ld<NTLOAD>(&O[(size_t)(4 * t + 4 + j) * 256]);
    }

    // compute A(t)
    float crow = __shfl(covv, t) * covscale;
    float mrow = __shfl(mskv, t);
    float acc = 0.f;
#pragma unroll
    for (int p = 0; p < 4; ++p) {
      f32x4 v4 = sv[p * 64 + lane];
      f32x4 x  = cur[p] + sdf[p * 64 + lane] + crow * swc[p * 64 + lane];
      acc += v4.x * ftanh(x.x);
      acc += v4.y * ftanh(x.y);
      acc += v4.z * ftanh(x.z);
      acc += v4.w * ftanh(x.w);
    }
#pragma unroll
    for (int o = 32; o > 0; o >>= 1) acc += __shfl_xor(acc, o);
    if (lane == 0) {
      float pw = __expf(acc - V) * mrow;
      pl[row] = pw;
      pout[row] = pw;
    }
    barrier_keep_loads();   // pl[4t..4t+3] visible; prefetches stay in flight

    // consume B(t); A(t+1) writes pl rows 4(t+1).. -> disjoint, safe
#pragma unroll
    for (int j = 0; j < 4; ++j)
      acc4 += pl[4 * t + j] * ob[j];
#pragma unroll
    for (int p = 0; p < 4; ++p) cur[p] = nxt[p];
#pragma unroll
    for (int j = 0; j < 4; ++j) ob[j] = obn[j];
  }

  *reinterpret_cast<f32x4*>(P4out + tid * 4) = acc4;
}

// K24: fused energy + ctx partial, 256 thr, 2560 blocks (2048 text 32-row
// chunks + 512 img). Text = NT loads (512 MB streams), img = cacheable
// (128 MB, L3-resident across replays).
__global__ __launch_bounds__(256) void k24_fused(
    const float* __restrict__ enc_features, const float* __restrict__ enc_img_features,
    const float* __restrict__ enc_outputs,  const float* __restrict__ enc_img_outputs,
    const float* __restrict__ coverage, const float* __restrict__ coverage_img,
    const float* __restrict__ enc_mask,
    const float* __restrict__ P1,
    const float* __restrict__ b1, const float* __restrict__ b2,
    const float* __restrict__ v1, const float* __restrict__ v2,
    const float* __restrict__ wc, const float* __restrict__ wci,
    const int* __restrict__ cov_set_p,
    float* __restrict__ p_all, float* __restrict__ P4) {
  __shared__ f32x4 sdf[256], sv[256], swc[256];
  __shared__ float pl[32];
  int bid = blockIdx.x, tid = threadIdx.x;
  float covscale = (float)(*cov_set_p);
  const float *feat, *osrc, *covsrc, *dfp, *bias, *vv, *wcp, *msk;
  float* pout;
  bool isText = (bid < 2048);
  if (isText) {
    int b = bid >> 5, row0b = (bid & 31) * 32;
    feat   = enc_features + ((size_t)b * 1024 + row0b) * 1024;
    osrc   = enc_outputs  + ((size_t)b * 1024 + row0b) * 1024;
    covsrc = coverage + (size_t)b * 1024 + row0b;
    msk    = enc_mask + (size_t)b * 1024 + row0b;
    pout   = p_all + (size_t)b * 1024 + row0b;
    dfp  = P1 + (size_t)b * 1024;                 // slabs 0..3
    bias = b1; vv = v1; wcp = wc;
  } else {
    int bi = bid - 2048;
    int b = bi >> 3, row0b = (bi & 7) * 32;
    feat   = enc_img_features + ((size_t)b * 256 + row0b) * 1024;
    osrc   = enc_img_outputs  + ((size_t)b * 256 + row0b) * 1024;
    covsrc = coverage_img + (size_t)b * 256 + row0b;
    msk    = nullptr;
    pout   = p_all + 65536 + (size_t)b * 256 + row0b;
    dfp  = P1 + 4 * 65536 + (size_t)b * 1024;     // slabs 4..7
    bias = b2; vv = v2; wcp = wci;
  }
  // stage operands: all 256 threads load df-sum + v + wc
  {
    const f32x4* P1v = reinterpret_cast<const f32x4*>(dfp);
    f32x4 s = P1v[tid] + P1v[16384 + tid] + P1v[32768 + tid] + P1v[49152 + tid];
    sdf[tid] = s + reinterpret_cast<const f32x4*>(bias)[tid];
    sv[tid]  = reinterpret_cast<const f32x4*>(vv)[tid];
    swc[tid] = reinterpret_cast<const f32x4*>(wcp)[tid];
  }
  __syncthreads();

  float* P4out = P4 + (size_t)bid * 1024;
  if (isText)
    k24_body<true>(feat, osrc, covsrc, msk, pout, P4out, covscale,
                   sdf, sv, swc, pl, tid);
  else
    k24_body<false>(feat, osrc, covsrc, msk, pout, P4out, covscale,
                    sdf, sv, swc, pl, tid);
}

// K34 (norm + ctx reduce): block = batch b (64 blocks).
// Text: 32 chunks/batch; img: 8 chunks/batch (P4 img base = 2048).
__global__ __launch_bounds__(256) void k34(
    const float* __restrict__ p_all, const float* __restrict__ P4,
    const float* __restrict__ coverage, const float* __restrict__ coverage_img,
    const int* __restrict__ cov_set_p,
    float* __restrict__ out, float* __restrict__ ctx) {
  __shared__ float redT[4], redI[4];
  int b   = blockIdx.x;
  int tid = threadIdx.x;
  float covscale = (float)(*cov_set_p);
  const float* pt = p_all + (size_t)b * 1024;
  const float* pi = p_all + 65536 + (size_t)b * 256;

  float pv[4];
  float st = 0.f;
#pragma unroll
  for (int k = 0; k < 4; ++k) {
    pv[k] = pt[k * 256 + tid];
    st += pv[k];
  }
  float piv = pi[tid];
  float si = piv;
#pragma unroll
  for (int o = 32; o > 0; o >>= 1) {
    st += __shfl_xor(st, o);
    si += __shfl_xor(si, o);
  }
  if ((tid & 63) == 0) {
    redT[tid >> 6] = st;
    redI[tid >> 6] = si;
  }
  __syncthreads();
  float invT = 1.f / (redT[0] + redT[1] + redT[2] + redT[3]);
  float invI = 1.f / (redI[0] + redI[1] + redI[2] + redI[3]);

  const float* covT = coverage + (size_t)b * 1024;
  const float* covI = coverage_img + (size_t)b * 256;
  float* attnT = out + 65536 + (size_t)b * 1024;
  float* covTo = out + 147456 + (size_t)b * 1024;
  float* attnI = out + 131072 + (size_t)b * 256;
  float* covIo = out + 212992 + (size_t)b * 256;
#pragma unroll
  for (int k = 0; k < 4; ++k) {
    int i = k * 256 + tid;
    float at = pv[k] * invT;
    attnT[i] = at;
    covTo[i] = covscale * covT[i] + at;
  }
  {
    float at = piv * invI;
    attnI[tid] = at;
    covIo[tid] = covscale * covI[tid] + at;
  }

  f32x4 accT = {0.f, 0.f, 0.f, 0.f};
#pragma unroll
  for (int c = 0; c < 32; ++c)
    accT += *reinterpret_cast<const f32x4*>(P4 + ((size_t)(b * 32 + c)) * 1024 + tid * 4);
  *reinterpret_cast<f32x4*>(ctx + (size_t)b * 1024 + tid * 4) = accT * invT;

  f32x4 accI = {0.f, 0.f, 0.f, 0.f};
#pragma unroll
  for (int c = 0; c < 8; ++c)
    accI += *reinterpret_cast<const f32x4*>(P4 + ((size_t)(2048 + b * 8 + c)) * 1024 + tid * 4);
  *reinterpret_cast<f32x4*>(ctx + 65536 + (size_t)b * 1024 + tid * 4) = accI * invI;
}

// K5: partials of ctx_t@WA (m=0), ctx_i@WB (m=1). grid = 256 blocks
// (m x 16 bg x 4 kq x 2 a-half), 128 thr; 0.5 MB W slab per block.
__global__ __launch_bounds__(128) void k5_gemm(
    const float* __restrict__ ctx,
    const float* __restrict__ WA, const float* __restrict__ WB,
    float* __restrict__ P5) {
  int bid = blockIdx.x;            // 0..255
  int m   = bid >> 7;              // 0..1
  int bg  = (bid >> 3) & 15;       // 0..15
  int kq  = (bid >> 1) & 3;        // 0..3
  int ah  = bid & 1;               // 0..1
  const float* W = m ? WB : WA;
  const float* dbase = ctx + (size_t)m * 65536 + kq * 256;
  const float* Wrow  = W + (size_t)(kq * 256) * A_DIM + ah * 512 + threadIdx.x * 4;

  f32x4 acc[4];
#pragma unroll
  for (int i = 0; i < 4; ++i) acc[i] = (f32x4){0.f, 0.f, 0.f, 0.f};

#pragma unroll 2
  for (int k4 = 0; k4 < 256; k4 += 4) {
    f32x4 w0 = *reinterpret_cast<const f32x4*>(Wrow + (size_t)(k4 + 0) * A_DIM);
    f32x4 w1 = *reinterpret_cast<const f32x4*>(Wrow + (size_t)(k4 + 1) * A_DIM);
    f32x4 w2 = *reinterpret_cast<const f32x4*>(Wrow + (size_t)(k4 + 2) * A_DIM);
    f32x4 w3 = *reinterpret_cast<const f32x4*>(Wrow + (size_t)(k4 + 3) * A_DIM);
#pragma unroll
    for (int i = 0; i < 4; ++i) {
      int b = bg * 4 + i;
      f32x4 d = *reinterpret_cast<const f32x4*>(dbase + (size_t)b * A_DIM + k4);
      acc[i] += d.x * w0;
      acc[i] += d.y * w1;
      acc[i] += d.z * w2;
      acc[i] += d.w * w3;
    }
  }
#pragma unroll
  for (int i = 0; i < 4; ++i) {
    int b = bg * 4 + i;
    *reinterpret_cast<f32x4*>(
        P5 + ((size_t)(m * 4 + kq) * 64 + b) * A_DIM + ah * 512 + threadIdx.x * 4) = acc[i];
  }
}

// K5b: ctx_mm = v3*tanh(g3+ctx_t@WA)*ctx_t + v4*tanh(g4+ctx_i@WB)*ctx_i
__global__ __launch_bounds__(256) void k5b_final(
    const float* __restrict__ P5, const float* __restrict__ P1,
    const float* __restrict__ b3, const float* __restrict__ b4,
    const float* __restrict__ ctx,
    const float* __restrict__ v3, const float* __restrict__ v4,
    float* __restrict__ out) {
  int tid = blockIdx.x * 256 + threadIdx.x;  // 0..65535
  int a = tid & 1023;
  size_t base = tid;
  float sA = P5[base] + P5[base + 65536] + P5[base + 2 * 65536] + P5[base + 3 * 65536];
  float sB = P5[base + 4 * 65536] + P5[base + 5 * 65536] + P5[base + 6 * 65536] +
             P5[base + 7 * 65536];
  float g3v = P1[8 * 65536 + base] + P1[9 * 65536 + base] +
              P1[10 * 65536 + base] + P1[11 * 65536 + base] + b3[a];
  float g4v = P1[12 * 65536 + base] + P1[13 * 65536 + base] +
              P1[14 * 65536 + base] + P1[15 * 65536 + base] + b4[a];
  float ct = ctx[base];
  float ci = ctx[65536 + base];
  float beta1 = v3[a] * ftanh(g3v + sA);
  float beta2 = v4[a] * ftanh(g4v + sB);
  out[tid] = beta1 * ct + beta2 * ci;
}

extern "C" void kernel_launch(void* const* d_in, const int* in_sizes, int n_in,
                              void* d_out, int out_size, void* d_ws, size_t ws_size,
                              hipStream_t stream) {
  const float* h0            = (const float*)d_in[0];
  const float* h1            = (const float*)d_in[1];
  const float* enc_outputs   = (const float*)d_in[2];
  const float* enc_features  = (const float*)d_in[3];
  const float* enc_mask      = (const float*)d_in[4];
  const float* coverage      = (const float*)d_in[5];
  const float* enc_img_outs  = (const float*)d_in[6];
  const float* enc_img_feats = (const float*)d_in[7];
  // d_in[8] = img_mask (unused by reference)
  const float* coverage_img  = (const float*)d_in[9];
  const int*   cov_set       = (const int*)d_in[10];
  const float* W1 = (const float*)d_in[11];
  const float* b1 = (const float*)d_in[12];
  const float* W2 = (const float*)d_in[13];
  const float* b2 = (const float*)d_in[14];
  const float* W3 = (const float*)d_in[15];
  const float* b3 = (const float*)d_in[16];
  const float* W4 = (const float*)d_in[17];
  const float* b4 = (const float*)d_in[18];
  const float* WA = (const float*)d_in[19];
  const float* WB = (const float*)d_in[20];
  const float* v1 = (const float*)d_in[21];
  const float* v2 = (const float*)d_in[22];
  const float* v3 = (const float*)d_in[23];
  const float* v4 = (const float*)d_in[24];
  const float* wc  = (const float*)d_in[25];
  const float* wci = (const float*)d_in[26];

  float* out = (float*)d_out;
  float* ws  = (float*)d_ws;

  float* P1    = ws + WS_P1_OFF;
  float* P4    = ws + WS_P4_OFF;
  float* P5    = ws + WS_P5_OFF;   // reuses P4 region (P4 dead after k34)
  float* p_all = ws + WS_PALL_OFF;
  float* ctx   = ws + WS_CTX_OFF;

  k1_gemm<<<dim3(512), dim3(128), 0, stream>>>(h0, h1, W1, W2, W3, W4, P1);
  k24_fused<<<dim3(2560), dim3(256), 0, stream>>>(
      enc_features, enc_img_feats, enc_outputs, enc_img_outs,
      coverage, coverage_img, enc_mask, P1, b1, b2,
      v1, v2, wc, wci, cov_set, p_all, P4);
  k34<<<dim3(64), dim3(256), 0, stream>>>(p_all, P4, coverage, coverage_img,
                                          cov_set, out, ctx);
  k5_gemm<<<dim3(256), dim3(128), 0, stream>>>(ctx, WA, WB, P5);
  k5b_final<<<dim3(256), dim3(256), 0, stream>>>(P5, P1, b3, b4, ctx, v3, v4, out);
}

// Round 16
// 156.543 us; speedup vs baseline: 1.0152x; 1.0152x over previous
//
#include <hip/hip_runtime.h>
#include <cstdint>

#define A_DIM 1024
#define B_DIM 64
#define H_DIM 512

typedef float f32x4 __attribute__((ext_vector_type(4)));

// ---------------- ws layout (float offsets) ----------------
// P1  : 16 slabs * 64 * 1024 = 1,048,576  [0]
//       slabs 0..3: df kq-partials (summed inline in k24)
//       slabs 4..7: dfi kq-partials (summed inline in k24)
//       slabs 8..15: g3/g4 partials (summed inline in k5b)
// P4  : 1280 * 1024 = 1,310,720  [1,048,576]   (ctx partials; dead after k34)
// P5  : 8 * 65536   =   524,288  [1,048,576]   (reuses P4 region)
// p_all: 65,536 + 16,384 = 81,920  [2,359,296]
// ctx : 2 * 65,536 = 131,072      [2,441,216]
#define WS_P1_OFF   0u
#define WS_P4_OFF   1048576u
#define WS_P5_OFF   1048576u
#define WS_PALL_OFF 2359296u
#define WS_CTX_OFF  2441216u

// d_out layout (floats): ctx_mm[0..65535], attn[65536..131071],
// attn_img[131072..147455], coverage[147456..212991], coverage_img[212992..229375]

__device__ __forceinline__ float ftanh(float x) {
  float xc = fminf(fmaxf(x, -10.f), 10.f);
  float t  = __expf(2.f * xc);
  return (t - 1.f) * __builtin_amdgcn_rcpf(t + 1.f);
}

// Execution-only barrier: lgkmcnt(0) orders LDS writes; vmcnt NOT drained, so
// register prefetches survive the rendezvous. sched_barrier stops hoisting.
__device__ __forceinline__ void barrier_keep_loads() {
  asm volatile("s_waitcnt lgkmcnt(0)" ::: "memory");
  __builtin_amdgcn_s_barrier();
  __builtin_amdgcn_sched_barrier(0);
}

template <bool NTLOAD>
__device__ __forceinline__ f32x4 stream_ld(const f32x4* p) {
  if constexpr (NTLOAD) return __builtin_nontemporal_load(p);
  else return *p;
}

// K1: partials of dec @ {W1..W4}. W rows VECTOR-coalesced, dec uniform
// s_loads. grid = 512 blocks (m x 16 bg x 4 kq x 2 a-half), 128 thr.
__global__ __launch_bounds__(128) void k1_gemm(
    const float* __restrict__ h0, const float* __restrict__ h1,
    const float* __restrict__ W1, const float* __restrict__ W2,
    const float* __restrict__ W3, const float* __restrict__ W4,
    float* __restrict__ P1) {
  int bid = blockIdx.x;            // 0..511
  int m   = bid >> 7;              // 0..3
  int bg  = (bid >> 3) & 15;       // 0..15 (4 batch rows each)
  int kq  = (bid >> 1) & 3;        // 0..3 (k-quarter of 256)
  int ah  = bid & 1;               // 0..1 (a-half of 512)
  const float* W = (m == 0) ? W1 : (m == 1) ? W2 : (m == 2) ? W3 : W4;
  const float* dbase = ((kq < 2) ? h0 : h1) + (kq & 1) * 256;
  const float* Wrow  = W + (size_t)(kq * 256) * A_DIM + ah * 512 + threadIdx.x * 4;

  f32x4 acc[4];
#pragma unroll
  for (int i = 0; i < 4; ++i) acc[i] = (f32x4){0.f, 0.f, 0.f, 0.f};

#pragma unroll 2
  for (int k4 = 0; k4 < 256; k4 += 4) {
    f32x4 w0 = *reinterpret_cast<const f32x4*>(Wrow + (size_t)(k4 + 0) * A_DIM);
    f32x4 w1 = *reinterpret_cast<const f32x4*>(Wrow + (size_t)(k4 + 1) * A_DIM);
    f32x4 w2 = *reinterpret_cast<const f32x4*>(Wrow + (size_t)(k4 + 2) * A_DIM);
    f32x4 w3 = *reinterpret_cast<const f32x4*>(Wrow + (size_t)(k4 + 3) * A_DIM);
#pragma unroll
    for (int i = 0; i < 4; ++i) {
      int b = bg * 4 + i;
      f32x4 d = *reinterpret_cast<const f32x4*>(dbase + (size_t)b * H_DIM + k4);
      acc[i] += d.x * w0;
      acc[i] += d.y * w1;
      acc[i] += d.z * w2;
      acc[i] += d.w * w3;
    }
  }
#pragma unroll
  for (int i = 0; i < 4; ++i) {
    int b = bg * 4 + i;
    *reinterpret_cast<f32x4*>(
        P1 + ((size_t)(m * 4 + kq) * 64 + b) * A_DIM + ah * 512 + threadIdx.x * 4) = acc[i];
  }
}

// K24 pipeline body: 8 subtiles of 8 rows, cross-subtile double-buffering of
// feat + O streams; barrier does not drain vmcnt. NTLOAD selects streaming
// (text: 512 MB, can't fit L3) vs cacheable (img: 128 MB, L3-resident).
template <bool NTLOAD>
__device__ __forceinline__ void k24_body(
    const float* feat, const float* osrc, const float* covsrc, const float* msk,
    float* pout, float* P4out, float covscale,
    f32x4* sdf, f32x4* sv, f32x4* swc, f32x4* sacc, float* pl,
    int tid) {
  int w = tid >> 6, lane = tid & 63;

  // cov/mask for this wave's rows (row(t) = 8t + w): lane t<8 holds row 8t+w.
  float covv = 0.f, mskv = 1.f;
  if (lane < 8) {
    int rr = 8 * lane + w;
    covv = covsrc[rr];
    mskv = msk ? msk[rr] : 1.f;
  }

  // V = sum_a |v_a| (deterministic, identical in every wave)
  float Vp = 0.f;
#pragma unroll
  for (int p = 0; p < 4; ++p) {
    f32x4 t = sv[p * 64 + lane];
    Vp += fabsf(t.x) + fabsf(t.y) + fabsf(t.z) + fabsf(t.w);
  }
#pragma unroll
  for (int o = 32; o > 0; o >>= 1) Vp += __shfl_xor(Vp, o);
  float V = Vp;

  const f32x4* F = reinterpret_cast<const f32x4*>(feat);
  int g2 = tid >> 8;        // 0/1: row parity for phase B
  int aq = tid & 255;       // a-quad for phase B
  const f32x4* O = reinterpret_cast<const f32x4*>(osrc) + aq;
  f32x4 acc4 = {0.f, 0.f, 0.f, 0.f};

  f32x4 cur[4], nxt[4], ob[4], obn[4];
  // prologue: subtile 0 loads
#pragma unroll
  for (int p = 0; p < 4; ++p)
    cur[p] = stream_ld<NTLOAD>(&F[(size_t)w * 256 + p * 64 + lane]);
#pragma unroll
  for (int j = 0; j < 4; ++j)
    ob[j] = stream_ld<NTLOAD>(&O[(size_t)(g2 + 2 * j) * 256]);

#pragma unroll
  for (int t = 0; t < 8; ++t) {
    int row = 8 * t + w;
    // prefetch subtile t+1 (both streams) — stays in flight across barrier
    if (t < 7) {
#pragma unroll
      for (int p = 0; p < 4; ++p)
        nxt[p] = stream_ld<NTLOAD>(&F[(size_t)(row + 8) * 256 + p * 64 + lane]);
#pragma unroll
      for (int j = 0; j < 4; ++j)
        obn[j] = stream_ld<NTLOAD>(&O[(size_t)(8 * t + 8 + g2 + 2 * j) * 256]);
    }

    // compute A(t)
    float crow = __shfl(covv, t) * covscale;
    float mrow = __shfl(mskv, t);
    float acc = 0.f;
#pragma unroll
    for (int p = 0; p < 4; ++p) {
      f32x4 v4 = sv[p * 64 + lane];
      f32x4 x  = cur[p] + sdf[p * 64 + lane] + crow * swc[p * 64 + lane];
      acc += v4.x * ftanh(x.x);
      acc += v4.y * ftanh(x.y);
      acc += v4.z * ftanh(x.z);
      acc += v4.w * ftanh(x.w);
    }
#pragma unroll
    for (int o = 32; o > 0; o >>= 1) acc += __shfl_xor(acc, o);
    if (lane == 0) {
      float pw = __expf(acc - V) * mrow;
      pl[row] = pw;
      pout[row] = pw;
    }
    barrier_keep_loads();   // pl[8t..8t+7] visible; prefetches stay in flight

    // consume B(t); next A writes pl rows 8(t+1).. -> disjoint, safe
#pragma unroll
    for (int j = 0; j < 4; ++j)
      acc4 += pl[8 * t + g2 + 2 * j] * ob[j];
#pragma unroll
    for (int p = 0; p < 4; ++p) cur[p] = nxt[p];
#pragma unroll
    for (int j = 0; j < 4; ++j) ob[j] = obn[j];
  }

  if (g2 == 1) sacc[aq] = acc4;
  __syncthreads();
  if (g2 == 0) {
    acc4 += sacc[aq];
    *reinterpret_cast<f32x4*>(P4out + aq * 4) = acc4;
  }
}

// K24: fused energy + ctx partial. Text blocks use NT loads (512 MB streams),
// img blocks use cacheable loads (128 MB, stays L3-resident across replays).
__global__ __launch_bounds__(512) void k24_fused(
    const float* __restrict__ enc_features, const float* __restrict__ enc_img_features,
    const float* __restrict__ enc_outputs,  const float* __restrict__ enc_img_outputs,
    const float* __restrict__ coverage, const float* __restrict__ coverage_img,
    const float* __restrict__ enc_mask,
    const float* __restrict__ P1,
    const float* __restrict__ b1, const float* __restrict__ b2,
    const float* __restrict__ v1, const float* __restrict__ v2,
    const float* __restrict__ wc, const float* __restrict__ wci,
    const int* __restrict__ cov_set_p,
    float* __restrict__ p_all, float* __restrict__ P4) {
  __shared__ f32x4 sdf[256], sv[256], swc[256];
  __shared__ f32x4 sacc[256];
  __shared__ float pl[64];
  int bid = blockIdx.x, tid = threadIdx.x;
  float covscale = (float)(*cov_set_p);
  const float *feat, *osrc, *covsrc, *dfp, *bias, *vv, *wcp, *msk;
  float* pout;
  bool isText = (bid < 1024);
  if (isText) {
    int b = bid >> 4, row0b = (bid & 15) * 64;
    feat   = enc_features + ((size_t)b * 1024 + row0b) * 1024;
    osrc   = enc_outputs  + ((size_t)b * 1024 + row0b) * 1024;
    covsrc = coverage + (size_t)b * 1024 + row0b;
    msk    = enc_mask + (size_t)b * 1024 + row0b;
    pout   = p_all + (size_t)b * 1024 + row0b;
    dfp  = P1 + (size_t)b * 1024;                 // slabs 0..3
    bias = b1; vv = v1; wcp = wc;
  } else {
    int bi = bid - 1024;
    int b = bi >> 2, row0b = (bi & 3) * 64;
    feat   = enc_img_features + ((size_t)b * 256 + row0b) * 1024;
    osrc   = enc_img_outputs  + ((size_t)b * 256 + row0b) * 1024;
    covsrc = coverage_img + (size_t)b * 256 + row0b;
    msk    = nullptr;
    pout   = p_all + 65536 + (size_t)b * 256 + row0b;
    dfp  = P1 + 4 * 65536 + (size_t)b * 1024;     // slabs 4..7
    bias = b2; vv = v2; wcp = wci;
  }
  // stage operands: threads 0..255 -> sdf (4-partial sum + bias),
  //                 256..511 -> sv+swc
  if (tid < 256) {
    const f32x4* P1v = reinterpret_cast<const f32x4*>(dfp);
    f32x4 s = P1v[tid] + P1v[16384 + tid] + P1v[32768 + tid] + P1v[49152 + tid];
    sdf[tid] = s + reinterpret_cast<const f32x4*>(bias)[tid];
  } else {
    int t = tid - 256;
    sv[t]  = reinterpret_cast<const f32x4*>(vv)[t];
    swc[t] = reinterpret_cast<const f32x4*>(wcp)[t];
  }
  __syncthreads();

  float* P4out = P4 + (size_t)bid * 1024;
  if (isText)
    k24_body<true>(feat, osrc, covsrc, msk, pout, P4out, covscale,
                   sdf, sv, swc, sacc, pl, tid);
  else
    k24_body<false>(feat, osrc, covsrc, msk, pout, P4out, covscale,
                    sdf, sv, swc, sacc, pl, tid);
}

// K34 (norm + ctx reduce): block = batch b (64 blocks).
__global__ __launch_bounds__(256) void k34(
    const float* __restrict__ p_all, const float* __restrict__ P4,
    const float* __restrict__ coverage, const float* __restrict__ coverage_img,
    const int* __restrict__ cov_set_p,
    float* __restrict__ out, float* __restrict__ ctx) {
  __shared__ float redT[4], redI[4];
  int b   = blockIdx.x;
  int tid = threadIdx.x;
  float covscale = (float)(*cov_set_p);
  const float* pt = p_all + (size_t)b * 1024;
  const float* pi = p_all + 65536 + (size_t)b * 256;

  float pv[4];
  float st = 0.f;
#pragma unroll
  for (int k = 0; k < 4; ++k) {
    pv[k] = pt[k * 256 + tid];
    st += pv[k];
  }
  float piv = pi[tid];
  float si = piv;
#pragma unroll
  for (int o = 32; o > 0; o >>= 1) {
    st += __shfl_xor(st, o);
    si += __shfl_xor(si, o);
  }
  if ((tid & 63) == 0) {
    redT[tid >> 6] = st;
    redI[tid >> 6] = si;
  }
  __syncthreads();
  float invT = 1.f / (redT[0] + redT[1] + redT[2] + redT[3]);
  float invI = 1.f / (redI[0] + redI[1] + redI[2] + redI[3]);

  const float* covT = coverage + (size_t)b * 1024;
  const float* covI = coverage_img + (size_t)b * 256;
  float* attnT = out + 65536 + (size_t)b * 1024;
  float* covTo = out + 147456 + (size_t)b * 1024;
  float* attnI = out + 131072 + (size_t)b * 256;
  float* covIo = out + 212992 + (size_t)b * 256;
#pragma unroll
  for (int k = 0; k < 4; ++k) {
    int i = k * 256 + tid;
    float at = pv[k] * invT;
    attnT[i] = at;
    covTo[i] = covscale * covT[i] + at;
  }
  {
    float at = piv * invI;
    attnI[tid] = at;
    covIo[tid] = covscale * covI[tid] + at;
  }

  f32x4 accT = {0.f, 0.f, 0.f, 0.f};
#pragma unroll
  for (int c = 0; c < 16; ++c)
    accT += *reinterpret_cast<const f32x4*>(P4 + ((size_t)(b * 16 + c)) * 1024 + tid * 4);
  *reinterpret_cast<f32x4*>(ctx + (size_t)b * 1024 + tid * 4) = accT * invT;

  f32x4 accI = {0.f, 0.f, 0.f, 0.f};
#pragma unroll
  for (int c = 0; c < 4; ++c)
    accI += *reinterpret_cast<const f32x4*>(P4 + ((size_t)(1024 + b * 4 + c)) * 1024 + tid * 4);
  *reinterpret_cast<f32x4*>(ctx + 65536 + (size_t)b * 1024 + tid * 4) = accI * invI;
}

// K5: partials of ctx_t@WA (m=0), ctx_i@WB (m=1). grid = 256 blocks
// (m x 16 bg x 4 kq x 2 a-half), 128 thr; 0.5 MB W slab per block.
__global__ __launch_bounds__(128) void k5_gemm(
    const float* __restrict__ ctx,
    const float* __restrict__ WA, const float* __restrict__ WB,
    float* __restrict__ P5) {
  int bid = blockIdx.x;            // 0..255
  int m   = bid >> 7;              // 0..1
  int bg  = (bid >> 3) & 15;       // 0..15
  int kq  = (bid >> 1) & 3;        // 0..3
  int ah  = bid & 1;               // 0..1
  const float* W = m ? WB : WA;
  const float* dbase = ctx + (size_t)m * 65536 + kq * 256;
  const float* Wrow  = W + (size_t)(kq * 256) * A_DIM + ah * 512 + threadIdx.x * 4;

  f32x4 acc[4];
#pragma unroll
  for (int i = 0; i < 4; ++i) acc[i] = (f32x4){0.f, 0.f, 0.f, 0.f};

#pragma unroll 2
  for (int k4 = 0; k4 < 256; k4 += 4) {
    f32x4 w0 = *reinterpret_cast<const f32x4*>(Wrow + (size_t)(k4 + 0) * A_DIM);
    f32x4 w1 = *reinterpret_cast<const f32x4*>(Wrow + (size_t)(k4 + 1) * A_DIM);
    f32x4 w2 = *reinterpret_cast<const f32x4*>(Wrow + (size_t)(k4 + 2) * A_DIM);
    f32x4 w3 = *reinterpret_cast<const f32x4*>(Wrow + (size_t)(k4 + 3) * A_DIM);
#pragma unroll
    for (int i = 0; i < 4; ++i) {
      int b = bg * 4 + i;
      f32x4 d = *reinterpret_cast<const f32x4*>(dbase + (size_t)b * A_DIM + k4);
      acc[i] += d.x * w0;
      acc[i] += d.y * w1;
      acc[i] += d.z * w2;
      acc[i] += d.w * w3;
    }
  }
#pragma unroll
  for (int i = 0; i < 4; ++i) {
    int b = bg * 4 + i;
    *reinterpret_cast<f32x4*>(
        P5 + ((size_t)(m * 4 + kq) * 64 + b) * A_DIM + ah * 512 + threadIdx.x * 4) = acc[i];
  }
}

// K5b: ctx_mm = v3*tanh(g3+ctx_t@WA)*ctx_t + v4*tanh(g4+ctx_i@WB)*ctx_i
__global__ __launch_bounds__(256) void k5b_final(
    const float* __restrict__ P5, const float* __restrict__ P1,
    const float* __restrict__ b3, const float* __restrict__ b4,
    const float* __restrict__ ctx,
    const float* __restrict__ v3, const float* __restrict__ v4,
    float* __restrict__ out) {
  int tid = blockIdx.x * 256 + threadIdx.x;  // 0..65535
  int a = tid & 1023;
  size_t base = tid;
  float sA = P5[base] + P5[base + 65536] + P5[base + 2 * 65536] + P5[base + 3 * 65536];
  float sB = P5[base + 4 * 65536] + P5[base + 5 * 65536] + P5[base + 6 * 65536] +
             P5[base + 7 * 65536];
  float g3v = P1[8 * 65536 + base] + P1[9 * 65536 + base] +
              P1[10 * 65536 + base] + P1[11 * 65536 + base] + b3[a];
  float g4v = P1[12 * 65536 + base] + P1[13 * 65536 + base] +
              P1[14 * 65536 + base] + P1[15 * 65536 + base] + b4[a];
  float ct = ctx[base];
  float ci = ctx[65536 + base];
  float beta1 = v3[a] * ftanh(g3v + sA);
  float beta2 = v4[a] * ftanh(g4v + sB);
  out[tid] = beta1 * ct + beta2 * ci;
}

extern "C" void kernel_launch(void* const* d_in, const int* in_sizes, int n_in,
                              void* d_out, int out_size, void* d_ws, size_t ws_size,
                              hipStream_t stream) {
  const float* h0            = (const float*)d_in[0];
  const float* h1            = (const float*)d_in[1];
  const float* enc_outputs   = (const float*)d_in[2];
  const float* enc_features  = (const float*)d_in[3];
  const float* enc_mask      = (const float*)d_in[4];
  const float* coverage      = (const float*)d_in[5];
  const float* enc_img_outs  = (const float*)d_in[6];
  const float* enc_img_feats = (const float*)d_in[7];
  // d_in[8] = img_mask (unused by reference)
  const float* coverage_img  = (const float*)d_in[9];
  const int*   cov_set       = (const int*)d_in[10];
  const float* W1 = (const float*)d_in[11];
  const float* b1 = (const float*)d_in[12];
  const float* W2 = (const float*)d_in[13];
  const float* b2 = (const float*)d_in[14];
  const float* W3 = (const float*)d_in[15];
  const float* b3 = (const float*)d_in[16];
  const float* W4 = (const float*)d_in[17];
  const float* b4 = (const float*)d_in[18];
  const float* WA = (const float*)d_in[19];
  const float* WB = (const float*)d_in[20];
  const float* v1 = (const float*)d_in[21];
  const float* v2 = (const float*)d_in[22];
  const float* v3 = (const float*)d_in[23];
  const float* v4 = (const float*)d_in[24];
  const float* wc  = (const float*)d_in[25];
  const float* wci = (const float*)d_in[26];

  float* out = (float*)d_out;
  float* ws  = (float*)d_ws;

  float* P1    = ws + WS_P1_OFF;
  float* P4    = ws + WS_P4_OFF;
  float* P5    = ws + WS_P5_OFF;   // reuses P4 region (P4 dead after k34)
  float* p_all = ws + WS_PALL_OFF;
  float* ctx   = ws + WS_CTX_OFF;

  k1_gemm<<<dim3(512), dim3(128), 0, stream>>>(h0, h1, W1, W2, W3, W4, P1);
  k24_fused<<<dim3(1280), dim3(512), 0, stream>>>(
      enc_features, enc_img_feats, enc_outputs, enc_img_outs,
      coverage, coverage_img, enc_mask, P1, b1, b2,
      v1, v2, wc, wci, cov_set, p_all, P4);
  k34<<<dim3(64), dim3(256), 0, stream>>>(p_all, P4, coverage, coverage_img,
                                          cov_set, out, ctx);
  k5_gemm<<<dim3(256), dim3(128), 0, stream>>>(ctx, WA, WB, P5);
  k5b_final<<<dim3(256), dim3(256), 0, stream>>>(P5, P1, b3, b4, ctx, v3, v4, out);
}